// Round 15
// baseline (1512.587 us; speedup 1.0000x reference)
//
#include <hip/hip_runtime.h>
#include <math.h>

// ---------------------------------------------------------------------------
// AttentionFlow v15.
//  v14 = best (1035us). fused<1> latency-bound at 1 blk/CU; register-wall
//  model refined: (512,4) splits 128 regs ~64 arch + 64 acc. v12 spilled on
//  the ARCH side (B-frags 32 + misc > 64). v15: 32-edge blocks (acc exactly
//  64 = ro+a3) + nt-PAIRED B loads (B-frags 32->16; A re-read per pair) to
//  squeeze arch <= 64. LDS 66KB/34KB -> 2 blocks/CU. Tail = v14.
// ---------------------------------------------------------------------------

#define NNODES 100000
#define DDIM   256
#define NH     512
#define NGROUP 64
#define EPG    1024
#define E1N    65536
#define E0N    65536
#define KTOP   256

typedef __attribute__((ext_vector_type(8))) _Float16 h8v;
typedef __attribute__((ext_vector_type(4))) float f32x4;

__device__ __forceinline__ float lrelu(float x) { return x > 0.0f ? x : 0.01f * x; }

__device__ __forceinline__ unsigned fenc(float f) {
  unsigned u = __float_as_uint(f);
  return (u & 0x80000000u) ? ~u : (u | 0x80000000u);
}
__device__ __forceinline__ float fdec(unsigned k) {
  unsigned u = (k & 0x80000000u) ? (k & 0x7FFFFFFFu) : ~k;
  return __uint_as_float(u);
}

__device__ __forceinline__ void splitf(float v, unsigned short& h, unsigned short& l) {
  _Float16 hh = (_Float16)v;
  _Float16 ll = (_Float16)(v - (float)hh);
  h = __builtin_bit_cast(unsigned short, hh);
  l = __builtin_bit_cast(unsigned short, ll);
}

__device__ __forceinline__ f32x4 mfma16(h8v a, h8v b, f32x4 c) {
  return __builtin_amdgcn_mfma_f32_16x16x32_f16(a, b, c, 0, 0, 0);
}

// split 8 f32 (two float4 bit-patterns) -> hi uint4 + lo uint4 (8 f16 each)
__device__ __forceinline__ void pack8(uint4 a, uint4 b, uint4& ph, uint4& pl) {
  float v[8] = {__uint_as_float(a.x), __uint_as_float(a.y),
                __uint_as_float(a.z), __uint_as_float(a.w),
                __uint_as_float(b.x), __uint_as_float(b.y),
                __uint_as_float(b.z), __uint_as_float(b.w)};
  unsigned short h[8], l[8];
#pragma unroll
  for (int d = 0; d < 8; ++d) splitf(v[d], h[d], l[d]);
  ph = make_uint4((unsigned)h[0] | ((unsigned)h[1] << 16),
                  (unsigned)h[2] | ((unsigned)h[3] << 16),
                  (unsigned)h[4] | ((unsigned)h[5] << 16),
                  (unsigned)h[6] | ((unsigned)h[7] << 16));
  pl = make_uint4((unsigned)l[0] | ((unsigned)l[1] << 16),
                  (unsigned)l[2] | ((unsigned)l[3] << 16),
                  (unsigned)l[4] | ((unsigned)l[5] << 16),
                  (unsigned)l[6] | ((unsigned)l[7] << 16));
}

// ---------------------------------------------------------------------------
// qterm[g][o] = b[o] + qs[g] @ W[512:768] + qr[g] @ W[768:1024]
// ---------------------------------------------------------------------------
__global__ __launch_bounds__(512)
void qterm_kernel(const float* __restrict__ qse, const float* __restrict__ qre,
                  const float* __restrict__ Wl, const float* __restrict__ bl,
                  const float* __restrict__ Wr, const float* __restrict__ br,
                  float* __restrict__ qtl, float* __restrict__ qtr)
{
  const int g = blockIdx.x;
  const int o = threadIdx.x;
  __shared__ float sq[DDIM];
  __shared__ float sr[DDIM];
  if (o < DDIM) sq[o] = qse[(size_t)g * DDIM + o];
  else          sr[o - DDIM] = qre[(size_t)g * DDIM + (o - DDIM)];
  __syncthreads();
  float al = bl[o], ar = br[o];
  for (int k = 0; k < DDIM; ++k) {
    float a = sq[k], b = sr[k];
    al += a * Wl[(size_t)(512 + k) * NH + o] + b * Wl[(size_t)(768 + k) * NH + o];
    ar += a * Wr[(size_t)(512 + k) * NH + o] + b * Wr[(size_t)(768 + k) * NH + o];
  }
  qtl[(size_t)g * NH + o] = al;
  qtr[(size_t)g * NH + o] = ar;
}

// ---------------------------------------------------------------------------
// weight prep: Wt{H,L}[o][k] = splitf16(W[k][o]) for Wl[0:512], Wr[0:512], Wc
// ---------------------------------------------------------------------------
__global__ __launch_bounds__(256)
void wprep_kernel(const float* __restrict__ Wl, const float* __restrict__ Wr,
                  const float* __restrict__ Wc,
                  unsigned short* __restrict__ WltH, unsigned short* __restrict__ WltL,
                  unsigned short* __restrict__ WrtH, unsigned short* __restrict__ WrtL,
                  unsigned short* __restrict__ WctH, unsigned short* __restrict__ WctL)
{
  __shared__ float shv[32][33];
  const int mtx = blockIdx.y;
  const int ti = blockIdx.x >> 4;     // k tile
  const int tj = blockIdx.x & 15;     // o tile
  const float* W = mtx == 0 ? Wl : (mtx == 1 ? Wr : Wc);
  unsigned short* OH = mtx == 0 ? WltH : (mtx == 1 ? WrtH : WctH);
  unsigned short* OL = mtx == 0 ? WltL : (mtx == 1 ? WrtL : WctL);
  const int t = threadIdx.x;
  const int r = t >> 3, c4 = (t & 7) * 4;
  *(float4*)&shv[r][c4] = *(const float4*)(W + (size_t)(ti * 32 + r) * 512 + tj * 32 + c4);
  __syncthreads();
  unsigned short h[4], l[4];
#pragma unroll
  for (int q = 0; q < 4; ++q) splitf(shv[c4 + q][r], h[q], l[q]);
  const size_t off = (size_t)(tj * 32 + r) * 512 + ti * 32 + c4;
  *(uint2*)(OH + off) = make_uint2((unsigned)h[0] | ((unsigned)h[1] << 16),
                                   (unsigned)h[2] | ((unsigned)h[3] << 16));
  *(uint2*)(OL + off) = make_uint2((unsigned)l[0] | ((unsigned)l[1] << 16),
                                   (unsigned)l[2] | ((unsigned)l[3] << 16));
}

// WlinT[o][k] = f16(Wlin[k][o]), 256x256, hi only
__global__ __launch_bounds__(256)
void wlinprep_kernel(const float* __restrict__ Wlin, unsigned short* __restrict__ WlinT)
{
  __shared__ float shv[32][33];
  const int ti = blockIdx.x >> 3;    // k tile
  const int tj = blockIdx.x & 7;     // o tile
  const int t = threadIdx.x;
  const int r = t >> 3, c4 = (t & 7) * 4;
  *(float4*)&shv[r][c4] = *(const float4*)(Wlin + (size_t)(ti * 32 + r) * 256 + tj * 32 + c4);
  __syncthreads();
  unsigned short o[4];
#pragma unroll
  for (int q = 0; q < 4; ++q)
    o[q] = __builtin_bit_cast(unsigned short, (_Float16)shv[c4 + q][r]);
  *(uint2*)(WlinT + (size_t)(tj * 32 + r) * 256 + ti * 32 + c4) =
      make_uint2((unsigned)o[0] | ((unsigned)o[1] << 16),
                 (unsigned)o[2] | ((unsigned)o[3] << 16));
}

// ---------------------------------------------------------------------------
// Fused score kernel, v15: 32 edges/block, 512 thr / 8 waves, wave = 32r x 64c
// (2mt x 4nt). (512,4): 128-reg budget; acc = ro+a3 = 64 exactly; arch kept
// <=64 via nt-PAIRED B loads (bh[2]+bl[2], A re-read per pair).
// LDS planes (hi [+ lo]), granule-swizzled: element (row,k) at ushort off
//   row*512 + ((k>>3)^(row&7))*8 + (k&7). Stage iterates PHYSICAL granules
// with inverse-swizzled global source.
// Row base select: base(idx) = (cntSel && cntSel[idx]>0) ? embA : embB.
// ---------------------------------------------------------------------------
template<int SPLIT>
__global__ __launch_bounds__(512, 4)
void fused_score_kernel(const int* __restrict__ edges,
                        const float* __restrict__ embA,
                        const float* __restrict__ embB,
                        const int* __restrict__ cntSel,
                        const float* __restrict__ rel,
                        const unsigned short* __restrict__ BrH,
                        const unsigned short* __restrict__ BrL,
                        const unsigned short* __restrict__ BcH,
                        const unsigned short* __restrict__ BcL,
                        const unsigned short* __restrict__ BlH,
                        const unsigned short* __restrict__ BlL,
                        const float* __restrict__ qtr,
                        const float* __restrict__ qtl,
                        const float* __restrict__ bcv,
                        float* __restrict__ logits,
                        unsigned* __restrict__ mkey)
{
  constexpr int NG = 2048;             // granules per plane (32 rows x 64)
  __shared__ uint4 planesv[(SPLIT ? 2 : 1) * NG];
  __shared__ float red[8][32];
  __shared__ int sidxJ[32], sidxI[32], sgrp[32];

  const int tid  = threadIdx.x;
  const int lane = tid & 63;
  const int w    = tid >> 6;
  const int arow = lane & 15;
  const int grp  = lane >> 4;
  const int col0 = w * 64;
  const int rb   = blockIdx.x * 32;

  const int srow = tid >> 4;           // 0..31
  const int gs   = tid & 15;
  const int ssw  = srow & 7;

  if (tid < 32) {
    const int* er = edges + (size_t)(rb + tid) * 8;
    sgrp[tid]  = er[0];
    sidxI[tid] = er[6];
    sidxJ[tid] = er[7];
  }
  __syncthreads();

  const float* baseR = rel + (size_t)(rb + srow) * DDIM - 256;

  auto rowbase = [&](int idx) -> const float* {
    const float* b = (cntSel && cntSel[idx] > 0) ? embA : embB;
    return b + (size_t)idx * DDIM;
  };

  auto stage = [&](const int* idxArr) {
    const float* bX = rowbase(idxArr[srow]);
#pragma unroll
    for (int q = 0; q < 4; ++q) {
      const int g  = q * 16 + gs;
      const int lg = g ^ ssw;
      const int kf = lg << 3;
      const float* s = (lg < 32) ? (bX + kf) : (baseR + kf);
      uint4 f0 = ((const uint4*)s)[0];
      uint4 f1 = ((const uint4*)s)[1];
      uint4 ph, pl;
      pack8(f0, f1, ph, pl);
      planesv[srow * 64 + g] = ph;
      if (SPLIT) planesv[NG + srow * 64 + g] = pl;
    }
  };

  stage(sidxJ);                        // A_j
  __syncthreads();

  const unsigned short* hiP = (const unsigned short*)planesv;
  const unsigned short* loP = hiP + (size_t)NG * 8;

  // nt-paired gemm: B frags only bh[2](+bl[2]); A re-read per pair.
  auto gemm = [&](const unsigned short* BH, const unsigned short* BL,
                  f32x4 (&acc)[2][4]) {
    for (int ks = 0; ks < 16; ++ks) {
      const int k0 = ks * 32 + grp * 8;
#pragma unroll
      for (int nh = 0; nh < 2; ++nh) {
        h8v bh[2], bl[2];
#pragma unroll
        for (int p = 0; p < 2; ++p) {
          const int nt = nh * 2 + p;
          const size_t boff = (size_t)(col0 + nt * 16 + arow) * 512 + k0;
          bh[p] = *(const h8v*)(BH + boff);
          if (SPLIT) bl[p] = *(const h8v*)(BL + boff);
        }
#pragma unroll
        for (int mt = 0; mt < 2; ++mt) {
          const int row = mt * 16 + arow;
          const int gh = (ks * 4 + grp) ^ (row & 7);
          h8v h = *(const h8v*)(hiP + row * 512 + gh * 8);
          h8v l;
          if (SPLIT) l = *(const h8v*)(loP + row * 512 + gh * 8);
#pragma unroll
          for (int p = 0; p < 2; ++p) {
            const int nt = nh * 2 + p;
            acc[mt][nt] = mfma16(h, bh[p], acc[mt][nt]);
            if (SPLIT) {
              acc[mt][nt] = mfma16(h, bl[p], acc[mt][nt]);
              acc[mt][nt] = mfma16(l, bh[p], acc[mt][nt]);
            }
          }
        }
      }
    }
  };

  // ---- GEMM1: A_j @ WrT ----
  f32x4 a1[2][4];
#pragma unroll
  for (int a = 0; a < 2; ++a)
#pragma unroll
    for (int b = 0; b < 4; ++b) a1[a][b] = (f32x4)0.0f;
  gemm(BrH, BrL, a1);
  __syncthreads();                     // all waves done reading A_j

  // Lr = leaky(a1 + qtr) -> planes (same swizzled layout)
  {
    unsigned short* hiW = (unsigned short*)planesv;
    unsigned short* loW = hiW + (size_t)NG * 8;
#pragma unroll
    for (int mt = 0; mt < 2; ++mt)
#pragma unroll
      for (int nt = 0; nt < 4; ++nt) {
        const int c = col0 + nt * 16 + arow;
#pragma unroll
        for (int reg = 0; reg < 4; ++reg) {
          const int row = mt * 16 + grp * 4 + reg;
          float v = lrelu(a1[mt][nt][reg] + qtr[(size_t)sgrp[row] * NH + c]);
          unsigned short h, l;
          splitf(v, h, l);
          const int off = row * 512 + (((c >> 3) ^ (row & 7)) << 3) + (c & 7);
          hiW[off] = h;
          if (SPLIT) loW[off] = l;
        }
      }
  }
  __syncthreads();

  // ---- GEMM2: Rout = Lr @ WcT + bc (registers) ----
  f32x4 ro[2][4];
#pragma unroll
  for (int a = 0; a < 2; ++a)
#pragma unroll
    for (int b = 0; b < 4; ++b) ro[a][b] = (f32x4)0.0f;
  gemm(BcH, BcL, ro);
#pragma unroll
  for (int nt = 0; nt < 4; ++nt) {
    const float bcval = bcv[col0 + nt * 16 + arow];
#pragma unroll
    for (int mt = 0; mt < 2; ++mt)
#pragma unroll
      for (int reg = 0; reg < 4; ++reg) ro[mt][nt][reg] += bcval;
  }
  __syncthreads();                     // all waves done reading Lr

  stage(sidxI);                        // A_i (overwrites Lr)
  __syncthreads();

  // ---- GEMM3 + fused dot vs Rout ----
  f32x4 a3[2][4];
#pragma unroll
  for (int a = 0; a < 2; ++a)
#pragma unroll
    for (int b = 0; b < 4; ++b) a3[a][b] = (f32x4)0.0f;
  gemm(BlH, BlL, a3);
#pragma unroll
  for (int mt = 0; mt < 2; ++mt) {
#pragma unroll
    for (int reg = 0; reg < 4; ++reg) {
      const int row = mt * 16 + grp * 4 + reg;
      const int g = sgrp[row];
      float s = 0.0f;
#pragma unroll
      for (int nt = 0; nt < 4; ++nt) {
        const int c = col0 + nt * 16 + arow;
        float v = lrelu(a3[mt][nt][reg] + qtl[(size_t)g * NH + c]);
        s += v * ro[mt][nt][reg];
      }
      s += __shfl_xor(s, 1); s += __shfl_xor(s, 2);
      s += __shfl_xor(s, 4); s += __shfl_xor(s, 8);
      if ((lane & 15) == 0) red[w][row] = s;
    }
  }
  __syncthreads();
  if (tid < 32) {
    float s = 0.0f;
#pragma unroll
    for (int p = 0; p < 8; ++p) s += red[p][tid];   // fixed order
    logits[rb + tid] = s;
    atomicMax(mkey + sidxI[tid], fenc(s));          // segment = er[6]
  }
}

// ---------------------------------------------------------------------------
// segment softmax helpers
// ---------------------------------------------------------------------------
__global__ void smax_exp_kernel(const int* __restrict__ edges, const float* __restrict__ logits,
                                const unsigned* __restrict__ mkey, float* __restrict__ ssum,
                                float* __restrict__ sm, int* __restrict__ cnt, int E)
{
  int e = blockIdx.x * blockDim.x + threadIdx.x;
  if (e < E) {
    int s = edges[(size_t)e * 8 + 6];
    float ev = expf(logits[e] - fdec(mkey[s]));
    sm[e] = ev;
    atomicAdd(ssum + s, ev);
    if (cnt) atomicAdd(cnt + edges[(size_t)e * 8 + 7], 1);
  }
}

__global__ void smax_norm_kernel(const int* __restrict__ edges, const float* __restrict__ ssum,
                                 float* __restrict__ sm, const float* __restrict__ nscore,
                                 float* __restrict__ ta, int E)
{
  int e = blockIdx.x * blockDim.x + threadIdx.x;
  if (e < E) {
    int s = edges[(size_t)e * 8 + 6];
    float v = sm[e] / ssum[s];
    sm[e] = v;
    if (ta) ta[e] = v * nscore[s];
  }
}

// ---------------------------------------------------------------------------
// per-group top-256 of 1024 (desc value, ties -> low idx), bitonic sort
// ---------------------------------------------------------------------------
__global__ __launch_bounds__(256)
void topk_kernel(const float* __restrict__ ta, const float* __restrict__ sm1,
                 const int* __restrict__ edges1,
                 float* __restrict__ out0, float* __restrict__ out2,
                 float* __restrict__ out3, float* __restrict__ smp,
                 int* __restrict__ prn_i, int* __restrict__ prn_j,
                 int* __restrict__ cnt1)
{
  __shared__ float v[EPG];
  __shared__ int   ix[EPG];
  const int g = blockIdx.x, tid = threadIdx.x;
  for (int t = tid; t < EPG; t += 256) { v[t] = ta[(size_t)g * EPG + t]; ix[t] = t; }
  __syncthreads();
  for (int k = 2; k <= EPG; k <<= 1) {
    for (int j = k >> 1; j > 0; j >>= 1) {
      for (int t = tid; t < EPG; t += 256) {
        int l = t ^ j;
        if (l > t) {
          float va = v[t], vb = v[l];
          int ia = ix[t], ib = ix[l];
          bool aFirst = (va > vb) || (va == vb && ia < ib);
          bool up = ((t & k) == 0);
          bool sw = up ? !aFirst : aFirst;
          if (sw) { v[t] = vb; ix[t] = ib; v[l] = va; ix[l] = ia; }
        }
      }
      __syncthreads();
    }
  }
  const int r = tid;
  const int oi = ix[r];
  const float val = v[r];
  const int orig = g * EPG + oi;
  out3[(size_t)g * KTOP + r] = (float)orig;
  const int* er = edges1 + (size_t)orig * 8;
#pragma unroll
  for (int c = 0; c < 8; ++c)
    out2[((size_t)(g * KTOP + r)) * 8 + c] = (float)er[c];
  const int ii = er[6], jj = er[7];
  const float smv = sm1[orig];
  smp[(size_t)g * KTOP + r] = smv;
  prn_i[(size_t)g * KTOP + r] = ii;
  prn_j[(size_t)g * KTOP + r] = jj;
  atomicAdd(out0 + jj, smv * val);
  atomicAdd(cnt1 + jj, 1);
}

// pass-1 pruned scatter: 4 edges per block; thread o = dim o (src = mememb)
__global__ void scatter_kernel(const int* __restrict__ idx_i,
                               const int* __restrict__ idx_j,
                               const float* __restrict__ w,
                               const float* __restrict__ semb,
                               float* __restrict__ agg)
{
  const int e0 = blockIdx.x * 4;
  const int o = threadIdx.x;
#pragma unroll
  for (int q = 0; q < 4; ++q) {
    const int e = e0 + q;
    const int i = idx_i[e];
    const int j = idx_j[e];
    atomicAdd(agg + (size_t)j * DDIM + o, w[e] * semb[(size_t)i * DDIM + o]);
  }
}

// pass-0 scatter: inline normalization + emb1 select (cnt1>0 ? agg1 : mememb)
__global__ void scatter0_kernel(const int* __restrict__ edges,
                                const float* __restrict__ sm,
                                const float* __restrict__ ssum,
                                const float* __restrict__ agg1,
                                const float* __restrict__ mememb,
                                const int* __restrict__ cnt1,
                                float* __restrict__ out)
{
  const int e0 = blockIdx.x * 4;
  const int o = threadIdx.x;
#pragma unroll
  for (int q = 0; q < 4; ++q) {
    const int e = e0 + q;
    const int i = edges[(size_t)e * 8 + 6];
    const int j = edges[(size_t)e * 8 + 7];
    const float wv = sm[e] / ssum[i];
    const float* src = ((cnt1[i] > 0) ? agg1 : mememb) + (size_t)i * DDIM;
    atomicAdd(out + (size_t)j * DDIM + o, wv * src[o]);
  }
}

// ---------------------------------------------------------------------------
// final (MFMA f16): out[r] = leaky( X[r] @ Wlin + blin )
//   X[r] = cnt0>0 ? agg0[r] : (cnt1>0 ? agg1[r] : mememb[r])
// ---------------------------------------------------------------------------
__global__ __launch_bounds__(512)
void final_mfma_kernel(const float* __restrict__ agg1, const float* __restrict__ mememb,
                       const int* __restrict__ cnt1,
                       const float* __restrict__ agg0, const int* __restrict__ cnt0,
                       const unsigned short* __restrict__ WlinT,
                       const float* __restrict__ blin, float* __restrict__ out)
{
  __shared__ int ssel[128];            // 0: mememb, 1: agg1, 2: agg0
  const int tid  = threadIdx.x;
  const int lane = tid & 63;
  const int wid  = tid >> 6;
  const int wm = wid >> 2, wn = wid & 3;
  const int rb = blockIdx.x * 128;
  const int arow = lane & 15;
  const int kgrp = (lane >> 4) * 8;
  const int row0 = wm * 64;
  const int col0 = wn * 64;

  if (tid < 128) {
    int r = rb + tid;
    int rc = (r < NNODES) ? r : 0;
    int s = 0;
    if (cnt0[rc] > 0) s = 2;
    else if (cnt1[rc] > 0) s = 1;
    ssel[tid] = s;
  }
  __syncthreads();

  f32x4 acc[4][4];
#pragma unroll
  for (int a = 0; a < 4; ++a)
#pragma unroll
    for (int b = 0; b < 4; ++b) acc[a][b] = (f32x4)0.0f;

  for (int ks = 0; ks < 8; ++ks) {
    const int k0 = ks * 32 + kgrp;
    h8v ah[4], bh[4];
#pragma unroll
    for (int nt = 0; nt < 4; ++nt)
      bh[nt] = *(const h8v*)(WlinT + (size_t)(col0 + nt * 16 + arow) * 256 + k0);
#pragma unroll
    for (int mt = 0; mt < 4; ++mt) {
      const int rl = row0 + mt * 16 + arow;
      int r = rb + rl;
      int rc = (r < NNODES) ? r : (NNODES - 1);
      const int sel = ssel[rl];
      const float* base = (sel == 2) ? agg0 : ((sel == 1) ? agg1 : mememb);
      const float* src = base + (size_t)rc * DDIM + k0;
      float4 f0 = *(const float4*)src;
      float4 f1 = *(const float4*)(src + 4);
      float v[8] = {f0.x, f0.y, f0.z, f0.w, f1.x, f1.y, f1.z, f1.w};
      h8v h;
#pragma unroll
      for (int d = 0; d < 8; ++d) h[d] = (_Float16)v[d];
      ah[mt] = h;
    }
#pragma unroll
    for (int mt = 0; mt < 4; ++mt)
#pragma unroll
      for (int nt = 0; nt < 4; ++nt)
        acc[mt][nt] = mfma16(ah[mt], bh[nt], acc[mt][nt]);
  }

  float bl4[4];
#pragma unroll
  for (int nt = 0; nt < 4; ++nt) bl4[nt] = blin[col0 + nt * 16 + arow];

#pragma unroll
  for (int mt = 0; mt < 4; ++mt)
#pragma unroll
    for (int reg = 0; reg < 4; ++reg) {
      const int r = rb + row0 + mt * 16 + (lane >> 4) * 4 + reg;
      if (r < NNODES) {
#pragma unroll
        for (int nt = 0; nt < 4; ++nt) {
          const int c = col0 + nt * 16 + arow;
          out[(size_t)r * DDIM + c] = lrelu(acc[mt][nt][reg] + bl4[nt]);
        }
      }
    }
}

// ---------------------------------------------------------------------------
extern "C" void kernel_launch(void* const* d_in, const int* in_sizes, int n_in,
                              void* d_out, int out_size, void* d_ws, size_t ws_size,
                              hipStream_t stream)
{
  (void)in_sizes; (void)n_in; (void)out_size; (void)ws_size;

  const float* node_score = (const float*)d_in[1];
  const int*   edges0 = (const int*)d_in[2];
  const int*   edges1 = (const int*)d_in[3];
  const float* rel0   = (const float*)d_in[4];
  const float* rel1   = (const float*)d_in[5];
  const float* mememb = (const float*)d_in[6];
  const float* qse    = (const float*)d_in[7];
  const float* qre    = (const float*)d_in[8];
  const float* Wl     = (const float*)d_in[9];
  const float* bl     = (const float*)d_in[10];
  const float* Wr     = (const float*)d_in[11];
  const float* br     = (const float*)d_in[12];
  const float* Wc     = (const float*)d_in[13];
  const float* bc     = (const float*)d_in[14];
  const float* Wlin   = (const float*)d_in[15];
  const float* blin   = (const float*)d_in[16];

  float* out0 = (float*)d_out;
  float* out1 = out0 + NNODES;
  float* out2 = out1 + (size_t)NNODES * DDIM;
  float* out3 = out2 + (size_t)NGROUP * KTOP * 8;

  char* wptr = (char*)d_ws;
  auto alloc = [&](size_t bytes) -> char* {
    char* p = wptr;
    wptr += (bytes + 255) & ~(size_t)255;
    return p;
  };
  float*    qtl     = (float*)alloc((size_t)NGROUP * NH * 4);
  float*    qtr     = (float*)alloc((size_t)NGROUP * NH * 4);
  float*    logits1 = (float*)alloc((size_t)E1N * 4);
  float*    sm1     = (float*)alloc((size_t)E1N * 4);
  float*    ta      = (float*)alloc((size_t)E1N * 4);
  float*    logits0 = (float*)alloc((size_t)E0N * 4);
  float*    sm0     = (float*)alloc((size_t)E0N * 4);
  unsigned* mkey    = (unsigned*)alloc((size_t)NNODES * 4);
  float*    ssum    = (float*)alloc((size_t)NNODES * 4);
  int*      cnt1    = (int*)alloc((size_t)NNODES * 4);
  int*      cnt0    = (int*)alloc((size_t)NNODES * 4);
  float*    smp     = (float*)alloc((size_t)NGROUP * KTOP * 4);
  int*      prn_i   = (int*)alloc((size_t)NGROUP * KTOP * 4);
  int*      prn_j   = (int*)alloc((size_t)NGROUP * KTOP * 4);
  float*    agg1    = (float*)alloc((size_t)NNODES * DDIM * 4);

  unsigned short* WltH = (unsigned short*)alloc((size_t)512 * 512 * 2);
  unsigned short* WltL = (unsigned short*)alloc((size_t)512 * 512 * 2);
  unsigned short* WrtH = (unsigned short*)alloc((size_t)512 * 512 * 2);
  unsigned short* WrtL = (unsigned short*)alloc((size_t)512 * 512 * 2);
  unsigned short* WctH = (unsigned short*)alloc((size_t)512 * 512 * 2);
  unsigned short* WctL = (unsigned short*)alloc((size_t)512 * 512 * 2);
  unsigned short* WlnT = (unsigned short*)alloc((size_t)256 * 256 * 2);

  // ---- pass 1 prep ----
  (void)hipMemsetAsync(agg1, 0, (size_t)NNODES * DDIM * 4, stream);
  (void)hipMemsetAsync(cnt1, 0, (size_t)NNODES * 4, stream);
  (void)hipMemsetAsync(mkey, 0, (size_t)NNODES * 4, stream);
  (void)hipMemsetAsync(ssum, 0, (size_t)NNODES * 4, stream);
  (void)hipMemsetAsync(out0, 0, (size_t)NNODES * 4, stream);

  qterm_kernel<<<NGROUP, 512, 0, stream>>>(qse, qre, Wl, bl, Wr, br, qtl, qtr);
  {
    dim3 g(256, 3);
    wprep_kernel<<<g, 256, 0, stream>>>(Wl, Wr, Wc, WltH, WltL, WrtH, WrtL, WctH, WctL);
  }
  wlinprep_kernel<<<64, 256, 0, stream>>>(Wlin, WlnT);

  // ---- pass 1: fused score (split-f16, exact-ish logits for top-k) ----
  fused_score_kernel<1><<<E1N / 32, 512, 0, stream>>>(
      edges1, mememb, mememb, nullptr, rel1,
      WrtH, WrtL, WctH, WctL, WltH, WltL,
      qtr, qtl, bc, logits1, mkey);

  smax_exp_kernel<<<E1N / 256, 256, 0, stream>>>(edges1, logits1, mkey, ssum, sm1,
                                                 nullptr, E1N);
  smax_norm_kernel<<<E1N / 256, 256, 0, stream>>>(edges1, ssum, sm1, node_score, ta, E1N);
  topk_kernel<<<NGROUP, 256, 0, stream>>>(ta, sm1, edges1, out0, out2, out3,
                                          smp, prn_i, prn_j, cnt1);
  scatter_kernel<<<NGROUP * KTOP / 4, 256, 0, stream>>>(prn_i, prn_j, smp,
                                                        mememb, agg1);

  // ---- pass 0 prep ----
  (void)hipMemsetAsync(mkey, 0, (size_t)NNODES * 4, stream);
  (void)hipMemsetAsync(ssum, 0, (size_t)NNODES * 4, stream);
  (void)hipMemsetAsync(cnt0, 0, (size_t)NNODES * 4, stream);
  (void)hipMemsetAsync(out1, 0, (size_t)NNODES * DDIM * 4, stream);

  // ---- pass 0: fused score (plain f16, continuous outputs) ----
  fused_score_kernel<0><<<E0N / 32, 512, 0, stream>>>(
      edges0, agg1, mememb, cnt1, rel0,
      WrtH, WrtL, WctH, WctL, WltH, WltL,
      qtr, qtl, bc, logits0, mkey);

  smax_exp_kernel<<<E0N / 256, 256, 0, stream>>>(edges0, logits0, mkey, ssum, sm0,
                                                 cnt0, E0N);
  scatter0_kernel<<<E0N / 4, 256, 0, stream>>>(edges0, sm0, ssum, agg1, mememb,
                                               cnt1, out1);
  final_mfma_kernel<<<(NNODES + 127) / 128, 512, 0, stream>>>(agg1, mememb, cnt1,
                                                              out1, cnt0,
                                                              WlnT, blin, out1);
}

// Round 16
// 1027.261 us; speedup vs baseline: 1.4724x; 1.4724x over previous
//
#include <hip/hip_runtime.h>
#include <math.h>

// ---------------------------------------------------------------------------
// AttentionFlow v16 = v14 (proven best, 1035us) + safe trims.
//  Register-wall settled (v11/v12/v15 all spill): GEMM3 needs ro+a3+frags
//  ~170 regs -> (512,2) / 64-row tile is the fused kernel's local optimum.
//  v16 adds: (1) #pragma unroll 2 on gemm ks-loop (hoist B L2 loads under
//  MFMAs); (2) agg1 memset -> zero only prn_j rows (read-guarded by cnt1>0);
//  (3) pass-1 smax_norm folded into topk (inline (sm/ssum)*nscore).
// ---------------------------------------------------------------------------

#define NNODES 100000
#define DDIM   256
#define NH     512
#define NGROUP 64
#define EPG    1024
#define E1N    65536
#define E0N    65536
#define KTOP   256

typedef __attribute__((ext_vector_type(8))) _Float16 h8v;
typedef __attribute__((ext_vector_type(4))) float f32x4;

__device__ __forceinline__ float lrelu(float x) { return x > 0.0f ? x : 0.01f * x; }

__device__ __forceinline__ unsigned fenc(float f) {
  unsigned u = __float_as_uint(f);
  return (u & 0x80000000u) ? ~u : (u | 0x80000000u);
}
__device__ __forceinline__ float fdec(unsigned k) {
  unsigned u = (k & 0x80000000u) ? (k & 0x7FFFFFFFu) : ~k;
  return __uint_as_float(u);
}

__device__ __forceinline__ void splitf(float v, unsigned short& h, unsigned short& l) {
  _Float16 hh = (_Float16)v;
  _Float16 ll = (_Float16)(v - (float)hh);
  h = __builtin_bit_cast(unsigned short, hh);
  l = __builtin_bit_cast(unsigned short, ll);
}

__device__ __forceinline__ f32x4 mfma16(h8v a, h8v b, f32x4 c) {
  return __builtin_amdgcn_mfma_f32_16x16x32_f16(a, b, c, 0, 0, 0);
}

// split 8 f32 (two float4 bit-patterns) -> hi uint4 + lo uint4 (8 f16 each)
__device__ __forceinline__ void pack8(uint4 a, uint4 b, uint4& ph, uint4& pl) {
  float v[8] = {__uint_as_float(a.x), __uint_as_float(a.y),
                __uint_as_float(a.z), __uint_as_float(a.w),
                __uint_as_float(b.x), __uint_as_float(b.y),
                __uint_as_float(b.z), __uint_as_float(b.w)};
  unsigned short h[8], l[8];
#pragma unroll
  for (int d = 0; d < 8; ++d) splitf(v[d], h[d], l[d]);
  ph = make_uint4((unsigned)h[0] | ((unsigned)h[1] << 16),
                  (unsigned)h[2] | ((unsigned)h[3] << 16),
                  (unsigned)h[4] | ((unsigned)h[5] << 16),
                  (unsigned)h[6] | ((unsigned)h[7] << 16));
  pl = make_uint4((unsigned)l[0] | ((unsigned)l[1] << 16),
                  (unsigned)l[2] | ((unsigned)l[3] << 16),
                  (unsigned)l[4] | ((unsigned)l[5] << 16),
                  (unsigned)l[6] | ((unsigned)l[7] << 16));
}

// ---------------------------------------------------------------------------
// qterm[g][o] = b[o] + qs[g] @ W[512:768] + qr[g] @ W[768:1024]
// ---------------------------------------------------------------------------
__global__ __launch_bounds__(512)
void qterm_kernel(const float* __restrict__ qse, const float* __restrict__ qre,
                  const float* __restrict__ Wl, const float* __restrict__ bl,
                  const float* __restrict__ Wr, const float* __restrict__ br,
                  float* __restrict__ qtl, float* __restrict__ qtr)
{
  const int g = blockIdx.x;
  const int o = threadIdx.x;
  __shared__ float sq[DDIM];
  __shared__ float sr[DDIM];
  if (o < DDIM) sq[o] = qse[(size_t)g * DDIM + o];
  else          sr[o - DDIM] = qre[(size_t)g * DDIM + (o - DDIM)];
  __syncthreads();
  float al = bl[o], ar = br[o];
  for (int k = 0; k < DDIM; ++k) {
    float a = sq[k], b = sr[k];
    al += a * Wl[(size_t)(512 + k) * NH + o] + b * Wl[(size_t)(768 + k) * NH + o];
    ar += a * Wr[(size_t)(512 + k) * NH + o] + b * Wr[(size_t)(768 + k) * NH + o];
  }
  qtl[(size_t)g * NH + o] = al;
  qtr[(size_t)g * NH + o] = ar;
}

// ---------------------------------------------------------------------------
// weight prep: Wt{H,L}[o][k] = splitf16(W[k][o]) for Wl[0:512], Wr[0:512], Wc
// ---------------------------------------------------------------------------
__global__ __launch_bounds__(256)
void wprep_kernel(const float* __restrict__ Wl, const float* __restrict__ Wr,
                  const float* __restrict__ Wc,
                  unsigned short* __restrict__ WltH, unsigned short* __restrict__ WltL,
                  unsigned short* __restrict__ WrtH, unsigned short* __restrict__ WrtL,
                  unsigned short* __restrict__ WctH, unsigned short* __restrict__ WctL)
{
  __shared__ float shv[32][33];
  const int mtx = blockIdx.y;
  const int ti = blockIdx.x >> 4;     // k tile
  const int tj = blockIdx.x & 15;     // o tile
  const float* W = mtx == 0 ? Wl : (mtx == 1 ? Wr : Wc);
  unsigned short* OH = mtx == 0 ? WltH : (mtx == 1 ? WrtH : WctH);
  unsigned short* OL = mtx == 0 ? WltL : (mtx == 1 ? WrtL : WctL);
  const int t = threadIdx.x;
  const int r = t >> 3, c4 = (t & 7) * 4;
  *(float4*)&shv[r][c4] = *(const float4*)(W + (size_t)(ti * 32 + r) * 512 + tj * 32 + c4);
  __syncthreads();
  unsigned short h[4], l[4];
#pragma unroll
  for (int q = 0; q < 4; ++q) splitf(shv[c4 + q][r], h[q], l[q]);
  const size_t off = (size_t)(tj * 32 + r) * 512 + ti * 32 + c4;
  *(uint2*)(OH + off) = make_uint2((unsigned)h[0] | ((unsigned)h[1] << 16),
                                   (unsigned)h[2] | ((unsigned)h[3] << 16));
  *(uint2*)(OL + off) = make_uint2((unsigned)l[0] | ((unsigned)l[1] << 16),
                                   (unsigned)l[2] | ((unsigned)l[3] << 16));
}

// WlinT[o][k] = f16(Wlin[k][o]), 256x256, hi only
__global__ __launch_bounds__(256)
void wlinprep_kernel(const float* __restrict__ Wlin, unsigned short* __restrict__ WlinT)
{
  __shared__ float shv[32][33];
  const int ti = blockIdx.x >> 3;    // k tile
  const int tj = blockIdx.x & 7;     // o tile
  const int t = threadIdx.x;
  const int r = t >> 3, c4 = (t & 7) * 4;
  *(float4*)&shv[r][c4] = *(const float4*)(Wlin + (size_t)(ti * 32 + r) * 256 + tj * 32 + c4);
  __syncthreads();
  unsigned short o[4];
#pragma unroll
  for (int q = 0; q < 4; ++q)
    o[q] = __builtin_bit_cast(unsigned short, (_Float16)shv[c4 + q][r]);
  *(uint2*)(WlinT + (size_t)(tj * 32 + r) * 256 + ti * 32 + c4) =
      make_uint2((unsigned)o[0] | ((unsigned)o[1] << 16),
                 (unsigned)o[2] | ((unsigned)o[3] << 16));
}

// ---------------------------------------------------------------------------
// Fused score kernel (v10/v14 config). Block = 64 edges x 512 cols,
// 512 thr / 8 waves; wave = 64r x 64c (4mt x 4nt). (512,2): no spill
// (measured 112 VGPR). LDS planes (hi [+ lo]), granule-swizzled:
// element (row,k) at ushort off = row*512 + ((k>>3)^(row&7))*8 + (k&7).
// T14: A_i gathered into regs before GEMM1, written to LDS after GEMM2.
// Row base select: base(idx) = (cntSel && cntSel[idx]>0) ? embA : embB.
// ---------------------------------------------------------------------------
template<int SPLIT>
__global__ __launch_bounds__(512, 2)
void fused_score_kernel(const int* __restrict__ edges,
                        const float* __restrict__ embA,
                        const float* __restrict__ embB,
                        const int* __restrict__ cntSel,
                        const float* __restrict__ rel,
                        const unsigned short* __restrict__ BrH,
                        const unsigned short* __restrict__ BrL,
                        const unsigned short* __restrict__ BcH,
                        const unsigned short* __restrict__ BcL,
                        const unsigned short* __restrict__ BlH,
                        const unsigned short* __restrict__ BlL,
                        const float* __restrict__ qtr,
                        const float* __restrict__ qtl,
                        const float* __restrict__ bcv,
                        float* __restrict__ logits,
                        unsigned* __restrict__ mkey)
{
  constexpr int NG = 4096;             // granules per plane (64 rows x 64)
  __shared__ uint4 planesv[(SPLIT ? 2 : 1) * NG];
  __shared__ float red[8][64];
  __shared__ int sidxJ[64], sidxI[64], sgrp[64];

  const int tid  = threadIdx.x;
  const int lane = tid & 63;
  const int w    = tid >> 6;
  const int arow = lane & 15;
  const int grp  = lane >> 4;
  const int col0 = w * 64;
  const int rb   = blockIdx.x * 64;

  const int srow = tid >> 3;           // 0..63
  const int gs   = tid & 7;
  const int ssw  = srow & 7;

  if (tid < 64) {
    const int* er = edges + (size_t)(rb + tid) * 8;
    sgrp[tid]  = er[0];
    sidxI[tid] = er[6];
    sidxJ[tid] = er[7];
  }
  __syncthreads();

  const float* baseR = rel + (size_t)(rb + srow) * DDIM - 256;

  auto rowbase = [&](int idx) -> const float* {
    const float* b = (cntSel && cntSel[idx] > 0) ? embA : embB;
    return b + (size_t)idx * DDIM;
  };

  // ---- T14: A_i gather into registers (consumed after GEMM2) ----
  uint4 ai[16];
  {
    const float* bI = rowbase(sidxI[srow]);
#pragma unroll
    for (int q = 0; q < 8; ++q) {
      const int lg = (q * 8 + gs) ^ ssw;
      const int kf = lg << 3;
      const float* s = (lg < 32) ? (bI + kf) : (baseR + kf);
      ai[2 * q]     = ((const uint4*)s)[0];
      ai[2 * q + 1] = ((const uint4*)s)[1];
    }
  }

  // ---- stage A_j ----
  {
    const float* bJ = rowbase(sidxJ[srow]);
#pragma unroll
    for (int q = 0; q < 8; ++q) {
      const int g  = q * 8 + gs;
      const int lg = g ^ ssw;
      const int kf = lg << 3;
      const float* s = (lg < 32) ? (bJ + kf) : (baseR + kf);
      uint4 f0 = ((const uint4*)s)[0];
      uint4 f1 = ((const uint4*)s)[1];
      uint4 ph, pl;
      pack8(f0, f1, ph, pl);
      planesv[srow * 64 + g] = ph;
      if (SPLIT) planesv[NG + srow * 64 + g] = pl;
    }
  }
  __syncthreads();

  const unsigned short* hiP = (const unsigned short*)planesv;
  const unsigned short* loP = hiP + (size_t)NG * 8;

  auto gemm = [&](const unsigned short* BH, const unsigned short* BL,
                  f32x4 (&acc)[4][4]) {
#pragma unroll 2
    for (int ks = 0; ks < 16; ++ks) {
      const int k0 = ks * 32 + grp * 8;
      h8v bh[4], bl[4];
#pragma unroll
      for (int nt = 0; nt < 4; ++nt) {
        const size_t boff = (size_t)(col0 + nt * 16 + arow) * 512 + k0;
        bh[nt] = *(const h8v*)(BH + boff);
        if (SPLIT) bl[nt] = *(const h8v*)(BL + boff);
      }
#pragma unroll
      for (int mt = 0; mt < 4; ++mt) {
        const int row = mt * 16 + arow;
        const int gh = (ks * 4 + grp) ^ (row & 7);
        h8v h = *(const h8v*)(hiP + row * 512 + gh * 8);
        h8v l;
        if (SPLIT) l = *(const h8v*)(loP + row * 512 + gh * 8);
#pragma unroll
        for (int nt = 0; nt < 4; ++nt) {
          acc[mt][nt] = mfma16(h, bh[nt], acc[mt][nt]);
          if (SPLIT) {
            acc[mt][nt] = mfma16(h, bl[nt], acc[mt][nt]);
            acc[mt][nt] = mfma16(l, bh[nt], acc[mt][nt]);
          }
        }
      }
    }
  };

  // ---- GEMM1: A_j @ WrT ----
  f32x4 a1[4][4];
#pragma unroll
  for (int a = 0; a < 4; ++a)
#pragma unroll
    for (int b = 0; b < 4; ++b) a1[a][b] = (f32x4)0.0f;
  gemm(BrH, BrL, a1);
  __syncthreads();                     // all waves done reading A_j

  // Lr = leaky(a1 + qtr) -> planes (same swizzled layout)
  {
    unsigned short* hiW = (unsigned short*)planesv;
    unsigned short* loW = hiW + (size_t)NG * 8;
#pragma unroll
    for (int mt = 0; mt < 4; ++mt)
#pragma unroll
      for (int nt = 0; nt < 4; ++nt) {
        const int c = col0 + nt * 16 + arow;
#pragma unroll
        for (int reg = 0; reg < 4; ++reg) {
          const int row = mt * 16 + grp * 4 + reg;
          float v = lrelu(a1[mt][nt][reg] + qtr[(size_t)sgrp[row] * NH + c]);
          unsigned short h, l;
          splitf(v, h, l);
          const int off = row * 512 + (((c >> 3) ^ (row & 7)) << 3) + (c & 7);
          hiW[off] = h;
          if (SPLIT) loW[off] = l;
        }
      }
  }
  __syncthreads();

  // ---- GEMM2: Rout = Lr @ WcT + bc (registers) ----
  f32x4 ro[4][4];
#pragma unroll
  for (int a = 0; a < 4; ++a)
#pragma unroll
    for (int b = 0; b < 4; ++b) ro[a][b] = (f32x4)0.0f;
  gemm(BcH, BcL, ro);
#pragma unroll
  for (int nt = 0; nt < 4; ++nt) {
    const float bcval = bcv[col0 + nt * 16 + arow];
#pragma unroll
    for (int mt = 0; mt < 4; ++mt)
#pragma unroll
      for (int reg = 0; reg < 4; ++reg) ro[mt][nt][reg] += bcval;
  }
  __syncthreads();                     // all waves done reading Lr

  // ---- write A_i (from regs) into planes ----
#pragma unroll
  for (int q = 0; q < 8; ++q) {
    uint4 ph, pl;
    pack8(ai[2 * q], ai[2 * q + 1], ph, pl);
    planesv[srow * 64 + q * 8 + gs] = ph;
    if (SPLIT) planesv[NG + srow * 64 + q * 8 + gs] = pl;
  }
  __syncthreads();

  // ---- GEMM3 + fused dot vs Rout ----
  f32x4 a3[4][4];
#pragma unroll
  for (int a = 0; a < 4; ++a)
#pragma unroll
    for (int b = 0; b < 4; ++b) a3[a][b] = (f32x4)0.0f;
  gemm(BlH, BlL, a3);
#pragma unroll
  for (int mt = 0; mt < 4; ++mt) {
#pragma unroll
    for (int reg = 0; reg < 4; ++reg) {
      const int row = mt * 16 + grp * 4 + reg;
      const int g = sgrp[row];
      float s = 0.0f;
#pragma unroll
      for (int nt = 0; nt < 4; ++nt) {
        const int c = col0 + nt * 16 + arow;
        float v = lrelu(a3[mt][nt][reg] + qtl[(size_t)g * NH + c]);
        s += v * ro[mt][nt][reg];
      }
      s += __shfl_xor(s, 1); s += __shfl_xor(s, 2);
      s += __shfl_xor(s, 4); s += __shfl_xor(s, 8);
      if ((lane & 15) == 0) red[w][row] = s;
    }
  }
  __syncthreads();
  if (tid < 64) {
    float s = 0.0f;
#pragma unroll
    for (int p = 0; p < 8; ++p) s += red[p][tid];   // fixed order
    logits[rb + tid] = s;
    atomicMax(mkey + sidxI[tid], fenc(s));          // segment = er[6]
  }
}

// ---------------------------------------------------------------------------
// segment softmax helper
// ---------------------------------------------------------------------------
__global__ void smax_exp_kernel(const int* __restrict__ edges, const float* __restrict__ logits,
                                const unsigned* __restrict__ mkey, float* __restrict__ ssum,
                                float* __restrict__ sm, int* __restrict__ cnt, int E)
{
  int e = blockIdx.x * blockDim.x + threadIdx.x;
  if (e < E) {
    int s = edges[(size_t)e * 8 + 6];
    float ev = expf(logits[e] - fdec(mkey[s]));
    sm[e] = ev;
    atomicAdd(ssum + s, ev);
    if (cnt) atomicAdd(cnt + edges[(size_t)e * 8 + 7], 1);
  }
}

// ---------------------------------------------------------------------------
// per-group top-256 of 1024 (desc value, ties -> low idx), bitonic sort.
// Normalization fused: v = (sm1/ssum[src]) * nscore[src] computed at load.
// ---------------------------------------------------------------------------
__global__ __launch_bounds__(256)
void topk_kernel(const float* __restrict__ sm1, const float* __restrict__ ssum,
                 const float* __restrict__ nscore,
                 const int* __restrict__ edges1,
                 float* __restrict__ out0, float* __restrict__ out2,
                 float* __restrict__ out3, float* __restrict__ smp,
                 int* __restrict__ prn_i, int* __restrict__ prn_j,
                 int* __restrict__ cnt1)
{
  __shared__ float v[EPG];
  __shared__ int   ix[EPG];
  const int g = blockIdx.x, tid = threadIdx.x;
  for (int t = tid; t < EPG; t += 256) {
    const int e = g * EPG + t;
    const int s = edges1[(size_t)e * 8 + 6];
    v[t] = (sm1[e] / ssum[s]) * nscore[s];
    ix[t] = t;
  }
  __syncthreads();
  for (int k = 2; k <= EPG; k <<= 1) {
    for (int j = k >> 1; j > 0; j >>= 1) {
      for (int t = tid; t < EPG; t += 256) {
        int l = t ^ j;
        if (l > t) {
          float va = v[t], vb = v[l];
          int ia = ix[t], ib = ix[l];
          bool aFirst = (va > vb) || (va == vb && ia < ib);
          bool up = ((t & k) == 0);
          bool sw = up ? !aFirst : aFirst;
          if (sw) { v[t] = vb; ix[t] = ib; v[l] = va; ix[l] = ia; }
        }
      }
      __syncthreads();
    }
  }
  const int r = tid;
  const int oi = ix[r];
  const float val = v[r];
  const int orig = g * EPG + oi;
  out3[(size_t)g * KTOP + r] = (float)orig;
  const int* er = edges1 + (size_t)orig * 8;
#pragma unroll
  for (int c = 0; c < 8; ++c)
    out2[((size_t)(g * KTOP + r)) * 8 + c] = (float)er[c];
  const int ii = er[6], jj = er[7];
  const float smv = sm1[orig] / ssum[ii];
  smp[(size_t)g * KTOP + r] = smv;
  prn_i[(size_t)g * KTOP + r] = ii;
  prn_j[(size_t)g * KTOP + r] = jj;
  atomicAdd(out0 + jj, smv * val);
  atomicAdd(cnt1 + jj, 1);
}

// zero agg1 rows listed in prn_j (duplicates write 0 concurrently: benign)
__global__ void zero_rows_kernel(const int* __restrict__ prn_j, float* __restrict__ agg)
{
  const int j = prn_j[blockIdx.x];
  agg[(size_t)j * DDIM + threadIdx.x] = 0.0f;
}

// pass-1 pruned scatter: 4 edges per block; thread o = dim o (src = mememb)
__global__ void scatter_kernel(const int* __restrict__ idx_i,
                               const int* __restrict__ idx_j,
                               const float* __restrict__ w,
                               const float* __restrict__ semb,
                               float* __restrict__ agg)
{
  const int e0 = blockIdx.x * 4;
  const int o = threadIdx.x;
#pragma unroll
  for (int q = 0; q < 4; ++q) {
    const int e = e0 + q;
    const int i = idx_i[e];
    const int j = idx_j[e];
    atomicAdd(agg + (size_t)j * DDIM + o, w[e] * semb[(size_t)i * DDIM + o]);
  }
}

// pass-0 scatter: inline normalization + emb1 select (cnt1>0 ? agg1 : mememb)
__global__ void scatter0_kernel(const int* __restrict__ edges,
                                const float* __restrict__ sm,
                                const float* __restrict__ ssum,
                                const float* __restrict__ agg1,
                                const float* __restrict__ mememb,
                                const int* __restrict__ cnt1,
                                float* __restrict__ out)
{
  const int e0 = blockIdx.x * 4;
  const int o = threadIdx.x;
#pragma unroll
  for (int q = 0; q < 4; ++q) {
    const int e = e0 + q;
    const int i = edges[(size_t)e * 8 + 6];
    const int j = edges[(size_t)e * 8 + 7];
    const float wv = sm[e] / ssum[i];
    const float* src = ((cnt1[i] > 0) ? agg1 : mememb) + (size_t)i * DDIM;
    atomicAdd(out + (size_t)j * DDIM + o, wv * src[o]);
  }
}

// ---------------------------------------------------------------------------
// final (MFMA f16): out[r] = leaky( X[r] @ Wlin + blin )
//   X[r] = cnt0>0 ? agg0[r] : (cnt1>0 ? agg1[r] : mememb[r])
// ---------------------------------------------------------------------------
__global__ __launch_bounds__(512)
void final_mfma_kernel(const float* __restrict__ agg1, const float* __restrict__ mememb,
                       const int* __restrict__ cnt1,
                       const float* __restrict__ agg0, const int* __restrict__ cnt0,
                       const unsigned short* __restrict__ WlinT,
                       const float* __restrict__ blin, float* __restrict__ out)
{
  __shared__ int ssel[128];            // 0: mememb, 1: agg1, 2: agg0
  const int tid  = threadIdx.x;
  const int lane = tid & 63;
  const int wid  = tid >> 6;
  const int wm = wid >> 2, wn = wid & 3;
  const int rb = blockIdx.x * 128;
  const int arow = lane & 15;
  const int kgrp = (lane >> 4) * 8;
  const int row0 = wm * 64;
  const int col0 = wn * 64;

  if (tid < 128) {
    int r = rb + tid;
    int rc = (r < NNODES) ? r : 0;
    int s = 0;
    if (cnt0[rc] > 0) s = 2;
    else if (cnt1[rc] > 0) s = 1;
    ssel[tid] = s;
  }
  __syncthreads();

  f32x4 acc[4][4];
#pragma unroll
  for (int a = 0; a < 4; ++a)
#pragma unroll
    for (int b = 0; b < 4; ++b) acc[a][b] = (f32x4)0.0f;

  for (int ks = 0; ks < 8; ++ks) {
    const int k0 = ks * 32 + kgrp;
    h8v ah[4], bh[4];
#pragma unroll
    for (int nt = 0; nt < 4; ++nt)
      bh[nt] = *(const h8v*)(WlinT + (size_t)(col0 + nt * 16 + arow) * 256 + k0);
#pragma unroll
    for (int mt = 0; mt < 4; ++mt) {
      const int rl = row0 + mt * 16 + arow;
      int r = rb + rl;
      int rc = (r < NNODES) ? r : (NNODES - 1);
      const int sel = ssel[rl];
      const float* base = (sel == 2) ? agg0 : ((sel == 1) ? agg1 : mememb);
      const float* src = base + (size_t)rc * DDIM + k0;
      float4 f0 = *(const float4*)src;
      float4 f1 = *(const float4*)(src + 4);
      float v[8] = {f0.x, f0.y, f0.z, f0.w, f1.x, f1.y, f1.z, f1.w};
      h8v h;
#pragma unroll
      for (int d = 0; d < 8; ++d) h[d] = (_Float16)v[d];
      ah[mt] = h;
    }
#pragma unroll
    for (int mt = 0; mt < 4; ++mt)
#pragma unroll
      for (int nt = 0; nt < 4; ++nt)
        acc[mt][nt] = mfma16(ah[mt], bh[nt], acc[mt][nt]);
  }

  float bl4[4];
#pragma unroll
  for (int nt = 0; nt < 4; ++nt) bl4[nt] = blin[col0 + nt * 16 + arow];

#pragma unroll
  for (int mt = 0; mt < 4; ++mt)
#pragma unroll
    for (int reg = 0; reg < 4; ++reg) {
      const int r = rb + row0 + mt * 16 + (lane >> 4) * 4 + reg;
      if (r < NNODES) {
#pragma unroll
        for (int nt = 0; nt < 4; ++nt) {
          const int c = col0 + nt * 16 + arow;
          out[(size_t)r * DDIM + c] = lrelu(acc[mt][nt][reg] + bl4[nt]);
        }
      }
    }
}

// ---------------------------------------------------------------------------
extern "C" void kernel_launch(void* const* d_in, const int* in_sizes, int n_in,
                              void* d_out, int out_size, void* d_ws, size_t ws_size,
                              hipStream_t stream)
{
  (void)in_sizes; (void)n_in; (void)out_size; (void)ws_size;

  const float* node_score = (const float*)d_in[1];
  const int*   edges0 = (const int*)d_in[2];
  const int*   edges1 = (const int*)d_in[3];
  const float* rel0   = (const float*)d_in[4];
  const float* rel1   = (const float*)d_in[5];
  const float* mememb = (const float*)d_in[6];
  const float* qse    = (const float*)d_in[7];
  const float* qre    = (const float*)d_in[8];
  const float* Wl     = (const float*)d_in[9];
  const float* bl     = (const float*)d_in[10];
  const float* Wr     = (const float*)d_in[11];
  const float* br     = (const float*)d_in[12];
  const float* Wc     = (const float*)d_in[13];
  const float* bc     = (const float*)d_in[14];
  const float* Wlin   = (const float*)d_in[15];
  const float* blin   = (const float*)d_in[16];

  float* out0 = (float*)d_out;
  float* out1 = out0 + NNODES;
  float* out2 = out1 + (size_t)NNODES * DDIM;
  float* out3 = out2 + (size_t)NGROUP * KTOP * 8;

  char* wptr = (char*)d_ws;
  auto alloc = [&](size_t bytes) -> char* {
    char* p = wptr;
    wptr += (bytes + 255) & ~(size_t)255;
    return p;
  };
  float*    qtl     = (float*)alloc((size_t)NGROUP * NH * 4);
  float*    qtr     = (float*)alloc((size_t)NGROUP * NH * 4);
  float*    logits1 = (float*)alloc((size_t)E1N * 4);
  float*    sm1     = (float*)alloc((size_t)E1N * 4);
  float*    logits0 = (float*)alloc((size_t)E0N * 4);
  float*    sm0     = (float*)alloc((size_t)E0N * 4);
  unsigned* mkey    = (unsigned*)alloc((size_t)NNODES * 4);
  float*    ssum    = (float*)alloc((size_t)NNODES * 4);
  int*      cnt1    = (int*)alloc((size_t)NNODES * 4);
  int*      cnt0    = (int*)alloc((size_t)NNODES * 4);
  float*    smp     = (float*)alloc((size_t)NGROUP * KTOP * 4);
  int*      prn_i   = (int*)alloc((size_t)NGROUP * KTOP * 4);
  int*      prn_j   = (int*)alloc((size_t)NGROUP * KTOP * 4);
  float*    agg1    = (float*)alloc((size_t)NNODES * DDIM * 4);

  unsigned short* WltH = (unsigned short*)alloc((size_t)512 * 512 * 2);
  unsigned short* WltL = (unsigned short*)alloc((size_t)512 * 512 * 2);
  unsigned short* WrtH = (unsigned short*)alloc((size_t)512 * 512 * 2);
  unsigned short* WrtL = (unsigned short*)alloc((size_t)512 * 512 * 2);
  unsigned short* WctH = (unsigned short*)alloc((size_t)512 * 512 * 2);
  unsigned short* WctL = (unsigned short*)alloc((size_t)512 * 512 * 2);
  unsigned short* WlnT = (unsigned short*)alloc((size_t)256 * 256 * 2);

  // ---- pass 1 prep (agg1 NOT memset: prn_j rows zeroed after topk) ----
  (void)hipMemsetAsync(cnt1, 0, (size_t)NNODES * 4, stream);
  (void)hipMemsetAsync(mkey, 0, (size_t)NNODES * 4, stream);
  (void)hipMemsetAsync(ssum, 0, (size_t)NNODES * 4, stream);
  (void)hipMemsetAsync(out0, 0, (size_t)NNODES * 4, stream);

  qterm_kernel<<<NGROUP, 512, 0, stream>>>(qse, qre, Wl, bl, Wr, br, qtl, qtr);
  {
    dim3 g(256, 3);
    wprep_kernel<<<g, 256, 0, stream>>>(Wl, Wr, Wc, WltH, WltL, WrtH, WrtL, WctH, WctL);
  }
  wlinprep_kernel<<<64, 256, 0, stream>>>(Wlin, WlnT);

  // ---- pass 1: fused score (split-f16, exact-ish logits for top-k) ----
  fused_score_kernel<1><<<E1N / 64, 512, 0, stream>>>(
      edges1, mememb, mememb, nullptr, rel1,
      WrtH, WrtL, WctH, WctL, WltH, WltL,
      qtr, qtl, bc, logits1, mkey);

  smax_exp_kernel<<<E1N / 256, 256, 0, stream>>>(edges1, logits1, mkey, ssum, sm1,
                                                 nullptr, E1N);
  topk_kernel<<<NGROUP, 256, 0, stream>>>(sm1, ssum, node_score, edges1,
                                          out0, out2, out3,
                                          smp, prn_i, prn_j, cnt1);
  zero_rows_kernel<<<NGROUP * KTOP, 256, 0, stream>>>(prn_j, agg1);
  scatter_kernel<<<NGROUP * KTOP / 4, 256, 0, stream>>>(prn_i, prn_j, smp,
                                                        mememb, agg1);

  // ---- pass 0 prep ----
  (void)hipMemsetAsync(mkey, 0, (size_t)NNODES * 4, stream);
  (void)hipMemsetAsync(ssum, 0, (size_t)NNODES * 4, stream);
  (void)hipMemsetAsync(cnt0, 0, (size_t)NNODES * 4, stream);
  (void)hipMemsetAsync(out1, 0, (size_t)NNODES * DDIM * 4, stream);

  // ---- pass 0: fused score (plain f16, continuous outputs) ----
  fused_score_kernel<0><<<E0N / 64, 512, 0, stream>>>(
      edges0, agg1, mememb, cnt1, rel0,
      WrtH, WrtL, WctH, WctL, WltH, WltL,
      qtr, qtl, bc, logits0, mkey);

  smax_exp_kernel<<<E0N / 256, 256, 0, stream>>>(edges0, logits0, mkey, ssum, sm0,
                                                 cnt0, E0N);
  scatter0_kernel<<<E0N / 4, 256, 0, stream>>>(edges0, sm0, ssum, agg1, mememb,
                                               cnt1, out1);
  final_mfma_kernel<<<(NNODES + 127) / 128, 512, 0, stream>>>(agg1, mememb, cnt1,
                                                              out1, cnt0,
                                                              WlnT, blin, out1);
}